// Round 1
// baseline (116.417 us; speedup 1.0000x reference)
//
#include <hip/hip_runtime.h>
#include <math.h>

// Beamline: drift(0.45) then 20x [quad(k_i, L=0.1), drift(0.9 or final 0.45)].
// Only final x,y matter (sample std, ddof=1). z-channel is dead; n_slices is
// mathematically irrelevant (quad matrices compose exactly: M(l)^5 = M(L_Q)).

#define LQ 0.1f
#define SIGMA_T 0.005

__global__ __launch_bounds__(256) void beamline_kernel(
    const float* __restrict__ x_in, const float* __restrict__ px_in,
    const float* __restrict__ y_in, const float* __restrict__ py_in,
    const float* __restrict__ pz_in, const float* __restrict__ k_set,
    int N, int Q, double* __restrict__ acc)
{
    __shared__ float ksh[64];
    for (int i = threadIdx.x; i < Q && i < 64; i += blockDim.x) ksh[i] = k_set[i];
    __syncthreads();

    float s1x = 0.f, s2x = 0.f, s1y = 0.f, s2y = 0.f;

    const int stride = gridDim.x * blockDim.x;
    for (int i = blockIdx.x * blockDim.x + threadIdx.x; i < N; i += stride) {
        float x  = x_in[i];
        float px = px_in[i];
        float y  = y_in[i];
        float py = py_in[i];
        float pz = pz_in[i];

        const float relp  = 1.0f + pz;
        const float invP  = 1.0f / relp;        // 1/(1+pz), once per particle
        const float s01   = invP * 0.01f;       // k -> u = k1n*LQ^2
        const float lqiP  = LQ * invP;          // a12 scale

        // first half drift (L = 0.45)
        {
            float Px = px * invP, Py = py * invP;
            float Pxy2 = fmaf(Px, Px, Py * Py);
            float rPl  = rsqrtf(1.0f - Pxy2);
            float t    = 0.45f * rPl;
            x = fmaf(Px, t, x);
            y = fmaf(Py, t, y);
        }

        for (int c = 0; c < Q; ++c) {
            const float k1 = ksh[c];
            // ---- quad, full length LQ, series in signed w = arg*LQ^2 ----
            // y-plane arg = +k1n, x-plane arg = -k1n ; u = k1n*LQ^2
            const float u  = k1 * s01;
            const float u2 = u * u;
            const float E  = fmaf(u2, 1.0f/24.0f,  1.0f);          // even cos part
            const float O  = u * fmaf(u2, 1.0f/720.0f, 0.5f);      // odd cos part
            const float cy = E + O;
            const float cx = E - O;
            const float Es = fmaf(u2, 1.0f/120.0f, 1.0f);          // even sinc part
            const float Os = u * fmaf(u2, 1.0f/5040.0f, 1.0f/6.0f);
            const float sy = Es + Os;                              // sin(skl)/(sqrt_k*LQ)
            const float sx = Es - Os;
            const float a12y = lqiP * sy;                          // sx/rel_p
            const float a12x = lqiP * sx;
            const float kf   = LQ * k1;                            // k1n*rel_p*LQ = k1*LQ
            const float a21y = kf * sy;                            // arg*sx*rel_p
            const float a21x = -kf * sx;

            float nx  = fmaf(cx, x,  a12x * px);
            float npx = fmaf(cx, px, a21x * x);
            float ny  = fmaf(cy, y,  a12y * py);
            float npy = fmaf(cy, py, a21y * y);
            x = nx; px = npx; y = ny; py = npy;

            // ---- drift: 0.9 between quads, 0.45 after the last ----
            const float L = (c == Q - 1) ? 0.45f : 0.9f;
            float Px = px * invP, Py = py * invP;
            float Pxy2 = fmaf(Px, Px, Py * Py);
            float rPl  = rsqrtf(1.0f - Pxy2);
            float t    = L * rPl;
            x = fmaf(Px, t, x);
            y = fmaf(Py, t, y);
        }

        s1x += x;
        s2x = fmaf(x, x, s2x);
        s1y += y;
        s2y = fmaf(y, y, s2y);
    }

    // ---- wave (64-lane) shuffle reduction ----
    for (int off = 32; off > 0; off >>= 1) {
        s1x += __shfl_down(s1x, off, 64);
        s2x += __shfl_down(s2x, off, 64);
        s1y += __shfl_down(s1y, off, 64);
        s2y += __shfl_down(s2y, off, 64);
    }

    __shared__ float red[4][4];
    const int lane = threadIdx.x & 63;
    const int wid  = threadIdx.x >> 6;
    if (lane == 0) {
        red[wid][0] = s1x; red[wid][1] = s2x;
        red[wid][2] = s1y; red[wid][3] = s2y;
    }
    __syncthreads();
    if (threadIdx.x == 0) {
        float a = 0.f, b = 0.f, c2 = 0.f, d = 0.f;
        const int nw = (blockDim.x + 63) >> 6;
        for (int w = 0; w < nw; ++w) {
            a  += red[w][0]; b  += red[w][1];
            c2 += red[w][2]; d  += red[w][3];
        }
        atomicAdd(&acc[0], (double)a);
        atomicAdd(&acc[1], (double)b);
        atomicAdd(&acc[2], (double)c2);
        atomicAdd(&acc[3], (double)d);
    }
}

__global__ void finalize_kernel(const double* __restrict__ acc,
                                float* __restrict__ out, int N)
{
    const double n  = (double)N;
    const double vx = (acc[1] - acc[0] * acc[0] / n) / (n - 1.0);
    const double vy = (acc[3] - acc[2] * acc[2] / n) / (n - 1.0);
    const double dx = sqrt(vx) - SIGMA_T;
    const double dy = sqrt(vy) - SIGMA_T;
    out[0] = (float)sqrt(dx * dx + dy * dy);
}

extern "C" void kernel_launch(void* const* d_in, const int* in_sizes, int n_in,
                              void* d_out, int out_size, void* d_ws, size_t ws_size,
                              hipStream_t stream) {
    const float* x_in  = (const float*)d_in[0];
    const float* px_in = (const float*)d_in[1];
    const float* y_in  = (const float*)d_in[2];
    const float* py_in = (const float*)d_in[3];
    // d_in[4] = z : dead for the output, never read
    const float* pz_in = (const float*)d_in[5];
    const float* k_set = (const float*)d_in[6];
    // d_in[7] = n_slices : result is independent of slicing (exact composition)

    const int N = in_sizes[0];
    const int Q = in_sizes[6];

    double* acc = (double*)d_ws;
    hipMemsetAsync(d_ws, 0, 4 * sizeof(double), stream);

    const int threads = 256;
    const int per_thread = 4;
    int blocks = (N + threads * per_thread - 1) / (threads * per_thread);
    if (blocks < 1) blocks = 1;

    beamline_kernel<<<blocks, threads, 0, stream>>>(
        x_in, px_in, y_in, py_in, pz_in, k_set, N, Q, acc);
    finalize_kernel<<<1, 1, 0, stream>>>(acc, (float*)d_out, N);
}